// Round 1
// baseline (697.011 us; speedup 1.0000x reference)
//
#include <hip/hip_runtime.h>
#include <hip/hip_bf16.h>

// GaussianConv: 5-layer KNN conv net on point cloud.
// N=100000 pts, N1=12500 clusters, K=8 neighbors.
// Layers (Cout): 256, 128, 64, 32, 3 ; Cin of gathered GEMM = 8*Cin_feat.
// Strategy: bf16 MFMA (16x16x32) gathered GEMM with 3-term hi/lo split for
// near-f32 accuracy; layer-0 pooling fused as deterministic fixed-point
// int32 atomics; sigmoid fused in epilogue.

typedef __attribute__((ext_vector_type(8))) __bf16 bf16x8;
typedef __attribute__((ext_vector_type(4))) float f32x4;
typedef __attribute__((ext_vector_type(8))) unsigned short u16x8;

#define NPTS 100000
#define N1PTS 12500

// Swizzled LDS offset for a [64 rows][64 k] bf16 tile:
// 16B-block index along k XORed with (row&7) -> breaks stride-128B bank conflicts.
__device__ __forceinline__ int swz(int r, int k) {
  return r * 64 + ((((k >> 3) ^ r) & 7) << 3) + (k & 7);
}

__global__ void prepack_w(const float* __restrict__ W, unsigned short* __restrict__ hi,
                          unsigned short* __restrict__ lo, int n) {
  int i = blockIdx.x * 256 + threadIdx.x;
  if (i >= n) return;
  float x = W[i];
  __bf16 h = (__bf16)x;
  __bf16 l = (__bf16)(x - (float)h);
  hi[i] = __builtin_bit_cast(unsigned short, h);
  lo[i] = __builtin_bit_cast(unsigned short, l);
}

__global__ void count_labels(const int* __restrict__ labels, int* __restrict__ cnt) {
  int i = blockIdx.x * 256 + threadIdx.x;
  if (i < NPTS) atomicAdd(&cnt[labels[i]], 1);
}

__global__ void finalize_pool(const int* __restrict__ pool, const int* __restrict__ cnt,
                              float* __restrict__ out) {
  int i = blockIdx.x * 256 + threadIdx.x;
  if (i >= N1PTS * 256) return;
  float denom = fmaxf((float)cnt[i >> 8], 1.0f);
  out[i] = ((float)pool[i]) * (1.0f / 16777216.0f) / denom;
}

// Generic gathered GEMM layer.
//   out[i, co] = act( sum_{j<8, c<Cin} in[gather(idx[i,j]), c] * W[co, j*Cin+c] + b[co] )
// ACT: sigmoid. POOL: instead of storing, fixed-point atomicAdd into pool[labels[i]*Cout+co].
// COMPOSED: gather row = labels[idx[i,j]] (upsample composition).
// SPLIT: 3-term bf16 hi/lo split (near-f32 accuracy).
template <bool ACT, bool POOL, bool COMPOSED, bool SPLIT>
__global__ __launch_bounds__(256, 2) void conv_gemm(
    const float* __restrict__ act_in, const int* __restrict__ idx,
    const int* __restrict__ lab, const unsigned short* __restrict__ Whi,
    const unsigned short* __restrict__ Wlo, const float* __restrict__ bias,
    float* __restrict__ out, int* __restrict__ pool,
    int M, int cinShift, int Cout, int Ktot) {
  __shared__ unsigned short sAhi[4096];
  __shared__ unsigned short sAlo[4096];
  __shared__ unsigned short sBhi[4096];
  __shared__ unsigned short sBlo[4096];

  const int Cin = 1 << cinShift;
  const int t = threadIdx.x;
  const int bm = blockIdx.x, bn = blockIdx.y;

  // staging decomposition: 256 threads cover 64 rows x 4 k-segments of 16
  const int sr = t >> 2;             // row (A) / col (B) within tile
  const int kseg = (t & 3) << 4;     // k offset within 64-wide chunk
  const int ai = bm * 64 + sr;       // global point row for A staging
  const int bco = bn * 64 + sr;      // global output channel for B staging

  f32x4 acc[4] = {};

  const int nch = Ktot >> 6;
  for (int kc = 0; kc < nch; ++kc) {
    const int kg = (kc << 6) + kseg;

    // ---- A tile: gather 16 consecutive f32, split into bf16 hi/lo
    float va[16];
#pragma unroll
    for (int e = 0; e < 16; ++e) va[e] = 0.0f;
    if (ai < M) {
      int j = kg >> cinShift;               // neighbor slot (uniform per thread)
      int nb = idx[ai * 8 + j];
      if (COMPOSED) nb = lab[nb];
      const float* src = act_in + ((size_t)nb << cinShift) + (kg & (Cin - 1));
      const float4* s4 = (const float4*)src;
#pragma unroll
      for (int q = 0; q < 4; ++q) {
        float4 v = s4[q];
        va[q * 4 + 0] = v.x; va[q * 4 + 1] = v.y;
        va[q * 4 + 2] = v.z; va[q * 4 + 3] = v.w;
      }
    }
    bf16x8 h0, h1, l0, l1;
#pragma unroll
    for (int e = 0; e < 8; ++e) {
      float x0 = va[e], x1 = va[e + 8];
      __bf16 a = (__bf16)x0; h0[e] = a; l0[e] = (__bf16)(x0 - (float)a);
      __bf16 b = (__bf16)x1; h1[e] = b; l1[e] = (__bf16)(x1 - (float)b);
    }

    // ---- B tile: pre-packed bf16 weights, row-major [Cout][Ktot]
    u16x8 bh0 = {}, bh1 = {}, bl0 = {}, bl1 = {};
    if (bco < Cout) {
      const unsigned short* sw = Whi + (size_t)bco * Ktot + kg;
      bh0 = ((const u16x8*)sw)[0];
      bh1 = ((const u16x8*)sw)[1];
      if (SPLIT) {
        const unsigned short* sl = Wlo + (size_t)bco * Ktot + kg;
        bl0 = ((const u16x8*)sl)[0];
        bl1 = ((const u16x8*)sl)[1];
      }
    }

    __syncthreads();  // previous chunk's compute done
    const int w0 = swz(sr, kseg), w1 = swz(sr, kseg + 8);
    *(bf16x8*)&sAhi[w0] = h0; *(bf16x8*)&sAhi[w1] = h1;
    *(u16x8*)&sBhi[w0] = bh0; *(u16x8*)&sBhi[w1] = bh1;
    if (SPLIT) {
      *(bf16x8*)&sAlo[w0] = l0; *(bf16x8*)&sAlo[w1] = l1;
      *(u16x8*)&sBlo[w0] = bl0; *(u16x8*)&sBlo[w1] = bl1;
    }
    __syncthreads();  // staging visible

    // ---- compute: 2 K-steps of 32; wave w owns cols [16w,16w+16)
    const int l = t & 63;
    const int lr = l & 15, lh = l >> 4;
    const int wid = t >> 6;
#pragma unroll
    for (int s = 0; s < 2; ++s) {
      const int kb = s * 32 + lh * 8;
      const int boff = swz(wid * 16 + lr, kb);
      bf16x8 bh = *(const bf16x8*)&sBhi[boff];
#pragma unroll
      for (int m = 0; m < 4; ++m) {
        const int aoff = swz(m * 16 + lr, kb);
        bf16x8 ah = *(const bf16x8*)&sAhi[aoff];
        acc[m] = __builtin_amdgcn_mfma_f32_16x16x32_bf16(ah, bh, acc[m], 0, 0, 0);
        if (SPLIT) {
          bf16x8 bl = *(const bf16x8*)&sBlo[boff];
          bf16x8 al = *(const bf16x8*)&sAlo[aoff];
          acc[m] = __builtin_amdgcn_mfma_f32_16x16x32_bf16(ah, bl, acc[m], 0, 0, 0);
          acc[m] = __builtin_amdgcn_mfma_f32_16x16x32_bf16(al, bh, acc[m], 0, 0, 0);
        }
      }
    }
  }

  // ---- epilogue: C frag (16x16x32): col = lane&15, row = (lane>>4)*4 + reg
  const int l = t & 63, wid = t >> 6;
  const int lr = l & 15, lh = l >> 4;
  const int co = bn * 64 + wid * 16 + lr;
  if (co < Cout) {
    const float bv = bias[co];
#pragma unroll
    for (int m = 0; m < 4; ++m) {
#pragma unroll
      for (int r = 0; r < 4; ++r) {
        const int i = bm * 64 + m * 16 + lh * 4 + r;
        if (i < M) {
          float z = acc[m][r] + bv;
          if (ACT) z = 1.0f / (1.0f + expf(-z));
          if (POOL) {
            atomicAdd(&pool[(size_t)lab[i] * Cout + co],
                      __float2int_rn(z * 16777216.0f));
          } else {
            out[(size_t)i * Cout + co] = z;
          }
        }
      }
    }
  }
}

extern "C" void kernel_launch(void* const* d_in, const int* in_sizes, int n_in,
                              void* d_out, int out_size, void* d_ws, size_t ws_size,
                              hipStream_t stream) {
  const float* features = (const float*)d_in[0];
  const int* knn0 = (const int*)d_in[1];
  const int* knn1 = (const int*)d_in[2];
  const int* labels = (const int*)d_in[3];
  const float* kw[5] = {(const float*)d_in[4], (const float*)d_in[6],
                        (const float*)d_in[8], (const float*)d_in[10],
                        (const float*)d_in[12]};
  const float* bw[5] = {(const float*)d_in[5], (const float*)d_in[7],
                        (const float*)d_in[9], (const float*)d_in[11],
                        (const float*)d_in[13]};

  char* ws = (char*)d_ws;
  size_t off = 0;
  auto alloc = [&](size_t bytes) -> void* {
    void* p = ws + off;
    off = (off + bytes + 255) & ~(size_t)255;
    return p;
  };
  const int wsz[5] = {524288, 262144, 65536, 16384, 768};  // weight elem counts
  const int wtotal = 869120;
  unsigned short* Whi = (unsigned short*)alloc((size_t)wtotal * 2);
  unsigned short* Wlo = (unsigned short*)alloc((size_t)wtotal * 2);
  int* pool = (int*)alloc((size_t)N1PTS * 256 * 4);
  int* cnt = (int*)alloc((size_t)N1PTS * 4);
  float* pooled = (float*)alloc((size_t)N1PTS * 256 * 4);
  float* f1 = (float*)alloc((size_t)N1PTS * 128 * 4);
  float* f2 = (float*)alloc((size_t)N1PTS * 64 * 4);
  float* f3 = (float*)alloc((size_t)NPTS * 32 * 4);
  if (off > ws_size) return;  // insufficient workspace -> fail loudly

  // 1. prepack all weights to bf16 hi/lo
  size_t woff = 0;
  for (int i = 0; i < 5; ++i) {
    prepack_w<<<(wsz[i] + 255) / 256, 256, 0, stream>>>(kw[i], Whi + woff, Wlo + woff, wsz[i]);
    woff += wsz[i];
  }

  // 2. zero pool + cnt (contiguous region), histogram labels
  hipMemsetAsync(pool, 0, (size_t)N1PTS * 256 * 4 + (size_t)N1PTS * 4, stream);
  count_labels<<<(NPTS + 255) / 256, 256, 0, stream>>>(labels, cnt);

  dim3 blk(256);
  // 3. layer 0: features[N,256] -> sigmoid -> fused fixed-point pool scatter
  conv_gemm<true, true, false, true><<<dim3(1563, 4), blk, 0, stream>>>(
      features, knn0, labels, Whi, Wlo, bw[0], nullptr, pool,
      NPTS, 8, 256, 2048);

  // 4. pooled mean [N1,256]
  finalize_pool<<<(N1PTS * 256 + 255) / 256, 256, 0, stream>>>(pool, cnt, pooled);

  // 5. layer 1: pooled -> f1 [N1,128]
  conv_gemm<true, false, false, true><<<dim3(196, 2), blk, 0, stream>>>(
      pooled, knn1, labels, Whi + 524288, Wlo + 524288, bw[1], f1, nullptr,
      N1PTS, 8, 128, 2048);

  // 6. layer 2: f1 -> f2 [N1,64]
  conv_gemm<true, false, false, true><<<dim3(196, 1), blk, 0, stream>>>(
      f1, knn1, labels, Whi + 786432, Wlo + 786432, bw[2], f2, nullptr,
      N1PTS, 7, 64, 1024);

  // 7. layer 3: gather f2[labels[knn0]] -> f3 [N,32]
  conv_gemm<true, false, true, true><<<dim3(1563, 1), blk, 0, stream>>>(
      f2, knn0, labels, Whi + 851968, Wlo + 851968, bw[3], f3, nullptr,
      NPTS, 6, 32, 512);

  // 8. layer 4: f3 -> out [N,3], no activation
  conv_gemm<false, false, false, true><<<dim3(1563, 1), blk, 0, stream>>>(
      f3, knn0, labels, Whi + 868352, Wlo + 868352, bw[4], (float*)d_out, nullptr,
      NPTS, 5, 3, 256);
}